// Round 3
// baseline (1413.669 us; speedup 1.0000x reference)
//
#include <hip/hip_runtime.h>
#include <hip/hip_bf16.h>

#define NNODES 100000
#define NEDGES 1600000
#define DIM 128
#define EDIM 16

#define SCAN_BLK 1024
#define NB1 ((NNODES + SCAN_BLK - 1) / SCAN_BLK)   // 98

// ---- ws layout (bytes). Total ~7.8 MB ----
#define O_CNT    0u          // int[NNODES]      degree histogram
#define O_RP     409600u     // int[NNODES+1]    row_ptr
#define O_CUR    819200u     // int[NNODES]      fill cursors
#define O_DINV   1228800u    // float[NNODES]    deg^{-1/2}
#define O_PART   1638400u    // int[NB1]         scan partials
#define O_PARTEX 1646592u    // int[NB1]         exclusive partials
#define O_CSR    1703936u    // int[NEDGES]      edge sources grouped by dst

__device__ __forceinline__ float bf_lo(unsigned p) { return __uint_as_float(p << 16); }
__device__ __forceinline__ float bf_hi(unsigned p) { return __uint_as_float(p & 0xFFFF0000u); }

// round-to-nearest-even f32 -> bf16 (as high 16 bits)
__device__ __forceinline__ unsigned rn_bf16(float x) {
    unsigned u = __float_as_uint(x);
    return (u + 0x7FFFu + ((u >> 16) & 1u)) >> 16;
}

__global__ __launch_bounds__(256) void hist_kernel(const int* __restrict__ dst,
                                                   int* __restrict__ cnt) {
    int e = blockIdx.x * 256 + threadIdx.x;
    if (e < NEDGES) atomicAdd(&cnt[dst[e]], 1);
}

__global__ __launch_bounds__(256) void scan_a(const int* __restrict__ cnt,
                                              int* __restrict__ rp,
                                              int* __restrict__ part) {
    __shared__ int s[256];
    const int b = blockIdx.x, t = threadIdx.x;
    const int base = b * SCAN_BLK + t * 4;
    int e0 = (base + 0 < NNODES) ? cnt[base + 0] : 0;
    int e1 = (base + 1 < NNODES) ? cnt[base + 1] : 0;
    int e2 = (base + 2 < NNODES) ? cnt[base + 2] : 0;
    int e3 = (base + 3 < NNODES) ? cnt[base + 3] : 0;
    int sum = e0 + e1 + e2 + e3;
    s[t] = sum;
    __syncthreads();
    for (int off = 1; off < 256; off <<= 1) {
        int x = (t >= off) ? s[t - off] : 0;
        __syncthreads();
        s[t] += x;
        __syncthreads();
    }
    int ex = s[t] - sum;
    if (base + 0 < NNODES) rp[base + 0] = ex;
    if (base + 1 < NNODES) rp[base + 1] = ex + e0;
    if (base + 2 < NNODES) rp[base + 2] = ex + e0 + e1;
    if (base + 3 < NNODES) rp[base + 3] = ex + e0 + e1 + e2;
    if (t == 255) part[b] = s[255];
}

__global__ __launch_bounds__(128) void scan_b(const int* __restrict__ part,
                                              int* __restrict__ partex) {
    __shared__ int sp[128];
    const int t = threadIdx.x;
    int v = (t < NB1) ? part[t] : 0;
    sp[t] = v;
    __syncthreads();
    for (int off = 1; off < 128; off <<= 1) {
        int x = (t >= off) ? sp[t - off] : 0;
        __syncthreads();
        sp[t] += x;
        __syncthreads();
    }
    if (t < NB1) partex[t] = sp[t] - v;
}

__global__ __launch_bounds__(256) void scan_c(int* __restrict__ rp,
                                              int* __restrict__ cur,
                                              const int* __restrict__ partex) {
    const int off = partex[blockIdx.x];
    const int t = threadIdx.x;
#pragma unroll
    for (int u = 0; u < 4; ++u) {
        int idx = blockIdx.x * SCAN_BLK + u * 256 + t;
        if (idx < NNODES) {
            int v = rp[idx] + off;
            rp[idx] = v;
            cur[idx] = v;
        }
    }
    if (blockIdx.x == 0 && t == 0) rp[NNODES] = NEDGES;
}

__global__ __launch_bounds__(256) void dinv_kernel(const int* __restrict__ cnt,
                                                   float* __restrict__ dinv) {
    int i = blockIdx.x * 256 + threadIdx.x;
    if (i < NNODES) {
        int c = cnt[i];
        dinv[i] = (c > 0) ? rsqrtf((float)c) : 0.0f;
    }
}

__global__ __launch_bounds__(256) void fill_kernel(const int* __restrict__ src,
                                                   const int* __restrict__ dst,
                                                   int* __restrict__ cur,
                                                   int* __restrict__ csr) {
    int e = blockIdx.x * 256 + threadIdx.x;
    if (e < NEDGES) {
        int d = dst[e];
        int pos = atomicAdd(&cur[d], 1);
        csr[pos] = src[e];
    }
}

// Fused gather-aggregate + 2-layer MLP. 128 threads/block, thread j = feature j.
// f32 weights are RN-packed to bf16 pairs in registers (64+64 VGPRs);
// activations broadcast via LDS (uniform addresses, conflict-free).
__global__ __launch_bounds__(128) void node_kernel(const int* __restrict__ rp,
                                                   const int* __restrict__ csr,
                                                   const float* __restrict__ dinv,
                                                   const float* __restrict__ nh,
                                                   const float* __restrict__ W1,
                                                   const float* __restrict__ b1,
                                                   const float* __restrict__ W2,
                                                   const float* __restrict__ b2,
                                                   float* __restrict__ out) {
    __shared__ float sA[DIM];
    __shared__ float sH[DIM];
    const int j = threadIdx.x;

    unsigned w1p[64], w2p[64];
#pragma unroll
    for (int k = 0; k < 64; ++k) {
        w1p[k] = rn_bf16(W1[(2 * k) * DIM + j]) | (rn_bf16(W1[(2 * k + 1) * DIM + j]) << 16);
        w2p[k] = rn_bf16(W2[(2 * k) * DIM + j]) | (rn_bf16(W2[(2 * k + 1) * DIM + j]) << 16);
    }
    const float bias1 = b1[j];
    const float bias2 = b2[j];

    for (int n = blockIdx.x; n < NNODES; n += gridDim.x) {
        const int beg = rp[n];
        const int end = rp[n + 1];
        const float dn = dinv[n];

        float acc = 0.0f;
        int i = beg;
        for (; i + 4 <= end; i += 4) {
            int s0 = csr[i + 0], s1 = csr[i + 1], s2 = csr[i + 2], s3 = csr[i + 3];
            float w0 = dinv[s0], w1 = dinv[s1], w2 = dinv[s2], w3 = dinv[s3];
            float f0 = nh[(size_t)s0 * DIM + j];
            float f1 = nh[(size_t)s1 * DIM + j];
            float f2 = nh[(size_t)s2 * DIM + j];
            float f3 = nh[(size_t)s3 * DIM + j];
            acc = fmaf(f0, w0, acc);
            acc = fmaf(f1, w1, acc);
            acc = fmaf(f2, w2, acc);
            acc = fmaf(f3, w3, acc);
        }
        for (; i < end; ++i) {
            int s = csr[i];
            acc = fmaf(nh[(size_t)s * DIM + j], dinv[s], acc);
        }

        sA[j] = acc * dn;
        __syncthreads();

        float acc1 = bias1;
        const float4* a4p = (const float4*)sA;
#pragma unroll
        for (int k = 0; k < 32; ++k) {
            float4 a4 = a4p[k];
            unsigned p0 = w1p[2 * k], p1 = w1p[2 * k + 1];
            acc1 += a4.x * bf_lo(p0);
            acc1 += a4.y * bf_hi(p0);
            acc1 += a4.z * bf_lo(p1);
            acc1 += a4.w * bf_hi(p1);
        }
        sH[j] = fmaxf(acc1, 0.0f);
        __syncthreads();

        float acc2 = bias2;
        const float4* h4p = (const float4*)sH;
#pragma unroll
        for (int k = 0; k < 32; ++k) {
            float4 a4 = h4p[k];
            unsigned p0 = w2p[2 * k], p1 = w2p[2 * k + 1];
            acc2 += a4.x * bf_lo(p0);
            acc2 += a4.y * bf_hi(p0);
            acc2 += a4.z * bf_lo(p1);
            acc2 += a4.w * bf_hi(p1);
        }
        out[(size_t)n * DIM + j] = acc2;
    }
}

extern "C" void kernel_launch(void* const* d_in, const int* in_sizes, int n_in,
                              void* d_out, int out_size, void* d_ws, size_t ws_size,
                              hipStream_t stream) {
    const float* nh = (const float*)d_in[0];   // f32 [NNODES, DIM]
    const float* eh = (const float*)d_in[1];   // f32 [NEDGES, EDIM]
    const int*   ei = (const int*)d_in[2];     // int32 [2, NEDGES]
    const float* W1 = (const float*)d_in[3];
    const float* b1 = (const float*)d_in[4];
    const float* W2 = (const float*)d_in[5];
    const float* b2 = (const float*)d_in[6];

    char* ws = (char*)d_ws;
    int*   cnt    = (int*)(ws + O_CNT);
    int*   rp     = (int*)(ws + O_RP);
    int*   cur    = (int*)(ws + O_CUR);
    float* dinv   = (float*)(ws + O_DINV);
    int*   part   = (int*)(ws + O_PART);
    int*   partex = (int*)(ws + O_PARTEX);
    int*   csr    = (int*)(ws + O_CSR);

    float* out_nh = (float*)d_out;
    float* out_eh = out_nh + (size_t)NNODES * DIM;

    const int* src = ei;
    const int* dst = ei + NEDGES;

    hipMemsetAsync(cnt, 0, (size_t)NNODES * sizeof(int), stream);

    hist_kernel<<<(NEDGES + 255) / 256, 256, 0, stream>>>(dst, cnt);
    scan_a<<<NB1, 256, 0, stream>>>(cnt, rp, part);
    scan_b<<<1, 128, 0, stream>>>(part, partex);
    scan_c<<<NB1, 256, 0, stream>>>(rp, cur, partex);
    dinv_kernel<<<(NNODES + 255) / 256, 256, 0, stream>>>(cnt, dinv);
    fill_kernel<<<(NEDGES + 255) / 256, 256, 0, stream>>>(src, dst, cur, csr);
    node_kernel<<<4096, 128, 0, stream>>>(rp, csr, dinv, nh, W1, b1, W2, b2, out_nh);

    hipMemcpyAsync(out_eh, eh, (size_t)NEDGES * EDIM * sizeof(float),
                   hipMemcpyDeviceToDevice, stream);
}